// Round 13
// baseline (554.543 us; speedup 1.0000x reference)
//
#include <hip/hip_runtime.h>
#include <math.h>

#define NN 25000
#define EE 400000
#define FF 128
#define DD 16
#define HH 64
#define HIDC 128
#define OUTC 32
#define GG 64
#define NODEBLK 782     // ceil(25000/32)  (k_sp precompute part)
#define SCATBLK 1563    // ceil(400000/256)
#define NTILES 1563     // ceil(25000/16)  (MFMA node tiles)

typedef __attribute__((ext_vector_type(8))) short short8;
typedef __attribute__((ext_vector_type(8))) unsigned short u16x8;
typedef __attribute__((ext_vector_type(4))) float f32x4;

union S8 { short8 v; unsigned short u[8]; };
union U8 { u16x8 v; unsigned short u[8]; };

__device__ __forceinline__ float silu_f(float v) {
    return v / (1.f + __expf(-v));
}

__device__ __forceinline__ unsigned short f2bf_rne(float f) {
  unsigned u = __float_as_uint(f);
  unsigned r = u + 0x7fffu + ((u >> 16) & 1u);
  return (unsigned short)(r >> 16);
}
__device__ __forceinline__ float bfbits2f(unsigned short b) {
  return __uint_as_float(((unsigned)b) << 16);
}

__device__ __forceinline__ void split8(const float* hv, S8& hi, S8& lo) {
#pragma unroll
  for (int j = 0; j < 8; ++j) {
    const unsigned short hb = (unsigned short)(__float_as_uint(hv[j]) >> 16);
    hi.u[j] = hb;
    lo.u[j] = f2bf_rne(hv[j] - bfbits2f(hb));
  }
}

// B[k=q*8+j][n=nc*16+m] fragment from row-major W (ldw = N), split hi/lo
__device__ __forceinline__ void loadBsplit(const float* __restrict__ W, int ldw,
                                           int k0, int n0, int q, int m,
                                           S8& bh, S8& bl) {
#pragma unroll
  for (int j = 0; j < 8; ++j) {
    const float wv = W[(size_t)(k0 + q * 8 + j) * ldw + n0 + m];
    const unsigned short hb = (unsigned short)(__float_as_uint(wv) >> 16);
    bh.u[j] = hb;
    bl.u[j] = f2bf_rne(wv - bfbits2f(hb));
  }
}

// 3-term split product: err ~2^-16 (near-fp32)
__device__ __forceinline__ f32x4 mfma3(const S8& ah, const S8& al,
                                       const S8& bh, const S8& bl, f32x4 c) {
  c = __builtin_amdgcn_mfma_f32_16x16x32_bf16(ah.v, bh.v, c, 0, 0, 0);
  c = __builtin_amdgcn_mfma_f32_16x16x32_bf16(al.v, bh.v, c, 0, 0, 0);
  c = __builtin_amdgcn_mfma_f32_16x16x32_bf16(ah.v, bl.v, c, 0, 0, 0);
  return c;
}

// ---------------- Sort step 1: histogram of dst ----------------
__global__ __launch_bounds__(256) void k_hist(
    const int* __restrict__ ei, int* __restrict__ cnt) {
  const int t = blockIdx.x * 256 + threadIdx.x;
  if (t < EE) atomicAdd(&cnt[ei[EE + t]], 1);
}

// ---------------- Sort step 2: exclusive scan ----------------
__global__ __launch_bounds__(1024) void k_scan(
    const int* __restrict__ cnt, int* __restrict__ row_ptr, int* __restrict__ next) {
  __shared__ int s[1024];
  const int t = threadIdx.x;
  const int base = t * 25;
  int loc[25];
  int sum = 0;
#pragma unroll
  for (int i = 0; i < 25; ++i) {
    const int n = base + i;
    loc[i] = (n < NN) ? cnt[n] : 0;
    sum += loc[i];
  }
  s[t] = sum;
  __syncthreads();
  for (int off = 1; off < 1024; off <<= 1) {
    const int v = (t >= off) ? s[t - off] : 0;
    __syncthreads();
    s[t] += v;
    __syncthreads();
  }
  int run = s[t] - sum;
#pragma unroll
  for (int i = 0; i < 25; ++i) {
    const int n = base + i;
    if (n < NN) {
      row_ptr[n] = run;
      next[n] = run;
      run += loc[i];
    }
  }
  if (t == 0) row_ptr[NN] = EE;
}

// ------- Fused: scatter (index-only) + layer-0 P precompute --------------------
__global__ __launch_bounds__(256) void k_sp(
    const int* __restrict__ ei, int* __restrict__ next,
    int* __restrict__ sdst, int* __restrict__ ssrc, int* __restrict__ seid,
    const float* __restrict__ X, const float* __restrict__ W,
    float* __restrict__ P1, unsigned short* __restrict__ P2h) {
  __shared__ __align__(16) float xT[4][128 * 12];
  if (blockIdx.x >= NODEBLK) {
    const int t = (blockIdx.x - NODEBLK) * 256 + threadIdx.x;
    if (t < EE) {
      const int d = ei[EE + t];
      const int slot = atomicAdd(&next[d], 1);
      sdst[slot] = d;
      ssrc[slot] = ei[t];
      seid[slot] = t;
    }
    return;
  }
  const int w = threadIdx.x >> 6, lane = threadIdx.x & 63;
  float* xt = xT[w];
  const int nb = (blockIdx.x * 4 + w) * 8;
#pragma unroll
  for (int e = 0; e < 8; ++e) {
    const int n = nb + e;
    const bool v = n < NN;
    xt[lane * 12 + e]        = v ? X[n * FF + lane] : 0.f;
    xt[(lane + 64) * 12 + e] = v ? X[n * FF + 64 + lane] : 0.f;
  }
  __syncthreads();
  float a1[8], a2[8];
#pragma unroll
  for (int e = 0; e < 8; ++e) { a1[e] = 0.f; a2[e] = 0.f; }
#pragma unroll 4
  for (int k = 0; k < 128; ++k) {
    const float wa = W[k * 64 + lane];
    const float wb = W[(128 + k) * 64 + lane];
    float xk[8];
    *(f32x4*)&xk[0] = *(const f32x4*)&xt[k * 12];
    *(f32x4*)&xk[4] = *(const f32x4*)&xt[k * 12 + 4];
#pragma unroll
    for (int e = 0; e < 8; ++e) {
      a1[e] = fmaf(xk[e], wa, a1[e]);
      a2[e] = fmaf(xk[e], wb, a2[e]);
    }
  }
#pragma unroll
  for (int e = 0; e < 8; ++e) {
    const int n = nb + e;
    if (n < NN) {
      P1[n * 64 + lane]  = a1[e];
      P2h[n * 64 + lane] = f2bf_rne(a2[e]);
    }
  }
}

// ---------------- K2: per-edge MLP via MFMA, dst-sorted, SW-pipelined ----------
// (256,4): 128 VGPR/wave budget. Explicit prefetch: issueIdx(g+1) at top of g,
// issueData(g+1) mid-compute; group-g gather results consumed one iteration
// after issue (vmcnt wait overlapped with compute). s_diff double-buffered.
template <bool COORD, bool GATHER>
__global__ __launch_bounds__(256, 4) void k_edge(
    const float* __restrict__ P1, const unsigned short* __restrict__ P2h,
    const float* __restrict__ pos, const float* __restrict__ eattr,
    unsigned short* __restrict__ seattr_h, const int* __restrict__ seid,
    const int* __restrict__ sdst, const int* __restrict__ ssrc,
    const float* __restrict__ mlp_w,
    const float* __restrict__ edge_w, const float* __restrict__ edge_b,
    const float* __restrict__ coord_w, const float* __restrict__ coord_b,
    float* __restrict__ e_agg, float* __restrict__ cu) {
  __shared__ __align__(16) float s_hs[4][16 * 76];
  __shared__ float s_diff[4][2][48];
  __shared__ float s_rad[4][16];
  __shared__ float s_red[4][16];
  const int tid = threadIdx.x, w = tid >> 6, lane = tid & 63;
  const int q = lane >> 4, m = lane & 15;

  S8 wB[2][4];
#pragma unroll
  for (int kc = 0; kc < 2; ++kc)
#pragma unroll
    for (int nc = 0; nc < 4; ++nc)
#pragma unroll
      for (int j = 0; j < 8; ++j)
        wB[kc][nc].u[j] = f2bf_rne(edge_w[(kc * 32 + q * 8 + j) * 64 + nc * 16 + m]);
  S8 w3B[4];
#pragma unroll
  for (int nc = 0; nc < 4; ++nc)
#pragma unroll
    for (int j = 0; j < 8; ++j)
      w3B[nc].u[j] = (lane < 32) ? f2bf_rne(mlp_w[256 * 64 + (q * 8 + j) * 64 + nc * 16 + m])
                                 : (unsigned short)0;
  float w4r[4], cwr[4], ebr[4];
#pragma unroll
  for (int nc = 0; nc < 4; ++nc) {
    w4r[nc] = mlp_w[272 * 64 + nc * 16 + m];
    ebr[nc] = edge_b[nc * 16 + m];
    cwr[nc] = COORD ? coord_w[nc * 16 + m] : 0.f;
  }
  const float cb = COORD ? coord_b[0] : 0.f;

  const int wave_id = blockIdx.x * 4 + w;               // 0..4095
  const int g0 = wave_id * 6 + (wave_id < 424 ? wave_id : 424);
  const int ng = (wave_id < 424) ? 7 : 6;

  const int pe = (lane < 48) ? (lane / 3) : 0;
  const int pc = lane - (lane / 3) * 3;

  // ---- prefetch register set ----
  int dmN, smN;
  f32x4 p1aN[2], p1bN[2];
  U8 p2rN[2];
  S8 eaN;

  auto issueIdx = [&](int g) {
    const int eb = (g0 + g) * 16;
    dmN = sdst[eb + m];
    smN = ssrc[eb + m];
  };
  auto issueData = [&](int g) {
    const int eb = (g0 + g) * 16;
#pragma unroll
    for (int kc = 0; kc < 2; ++kc) {
      const float* pp1 = P1 + (size_t)dmN * 64 + kc * 32 + q * 8;
      p1aN[kc] = *(const f32x4*)pp1;
      p1bN[kc] = *(const f32x4*)(pp1 + 4);
      p2rN[kc].v = *(const u16x8*)(P2h + (size_t)smN * 64 + kc * 32 + q * 8);
    }
    if (lane < 48) {
      const int de = __shfl(dmN, pe, 64), se = __shfl(smN, pe, 64);
      s_diff[w][g & 1][lane] = pos[de * 3 + pc] - pos[se * 3 + pc];
    }
#pragma unroll
    for (int j = 0; j < 8; ++j) eaN.u[j] = 0;
    if (lane < 32) {
      if (GATHER) {
        const int eid = seid[eb + m];
        const float* ep = &eattr[(size_t)eid * DD + q * 8];
        const f32x4 ea0 = *(const f32x4*)ep;
        const f32x4 ea1 = *(const f32x4*)(ep + 4);
#pragma unroll
        for (int j = 0; j < 4; ++j) {
          eaN.u[j]     = f2bf_rne(ea0[j]);
          eaN.u[4 + j] = f2bf_rne(ea1[j]);
        }
        *(short8*)&seattr_h[(size_t)(eb + m) * DD + q * 8] = eaN.v;
      } else {
        eaN.v = *(const short8*)&seattr_h[(size_t)(eb + m) * DD + q * 8];
      }
    }
  };

  issueIdx(0);
  issueData(0);

  int cur_dst = -1;
  float accum = 0.f;

  for (int g = 0; g < ng; ++g) {
    const int buf = g & 1;
    const int dm = dmN;       // current-group copies (taken before overwrite)
    const S8 eaA = eaN;
    if (g + 1 < ng) issueIdx(g + 1);

    // radial from staged diffs (committed by issueData(g) last iteration)
    if (lane < 16) {
      const float d0 = s_diff[w][buf][lane * 3 + 0];
      const float d1 = s_diff[w][buf][lane * 3 + 1];
      const float d2 = s_diff[w][buf][lane * 3 + 2];
      s_rad[w][lane] = fmaf(d0, d0, fmaf(d1, d1, d2 * d2));
    }
    float radr[4];
#pragma unroll
    for (int r = 0; r < 4; ++r) radr[r] = s_rad[w][q * 4 + r];
    f32x4 c3[4];
#pragma unroll
    for (int nc = 0; nc < 4; ++nc) {
      f32x4 z = {0.f, 0.f, 0.f, 0.f};
      c3[nc] = __builtin_amdgcn_mfma_f32_16x16x32_bf16(eaA.v, w3B[nc].v, z, 0, 0, 0);
    }
#pragma unroll
    for (int nc = 0; nc < 4; ++nc)
#pragma unroll
      for (int r = 0; r < 4; ++r)
        s_hs[w][(q * 4 + r) * 76 + nc * 16 + m] = fmaf(radr[r], w4r[nc], c3[nc][r]);

    // consume group-g gathers (issued one iteration ago), then issue g+1
    f32x4 p1a[2] = {p1aN[0], p1aN[1]};
    f32x4 p1b[2] = {p1bN[0], p1bN[1]};
    U8 p2r[2];
    p2r[0] = p2rN[0]; p2r[1] = p2rN[1];
    if (g + 1 < ng) issueData(g + 1);

    S8 ahi[2], alo[2];
#pragma unroll
    for (int kc = 0; kc < 2; ++kc) {
      const float* hp = &s_hs[w][m * 76 + kc * 32 + q * 8];
      f32x4 h0 = *(const f32x4*)hp;
      f32x4 h1 = *(const f32x4*)(hp + 4);
      h0 = h0 + p1a[kc];
      h1 = h1 + p1b[kc];
      float hv[8];
      *(f32x4*)&hv[0] = h0;
      *(f32x4*)&hv[4] = h1;
#pragma unroll
      for (int j = 0; j < 8; ++j) {
        const float h = silu_f(hv[j] + bfbits2f(p2r[kc].u[j]));
        const unsigned short hb = (unsigned short)(__float_as_uint(h) >> 16);
        ahi[kc].u[j] = hb;
        alo[kc].u[j] = f2bf_rne(h - bfbits2f(hb));
      }
    }
    f32x4 o[4];
#pragma unroll
    for (int nc = 0; nc < 4; ++nc) {
      f32x4 bi = {ebr[nc], ebr[nc], ebr[nc], ebr[nc]};
      o[nc] = bi;
    }
#pragma unroll
    for (int kc = 0; kc < 2; ++kc)
#pragma unroll
      for (int nc = 0; nc < 4; ++nc) {
        o[nc] = __builtin_amdgcn_mfma_f32_16x16x32_bf16(ahi[kc].v, wB[kc][nc].v, o[nc], 0, 0, 0);
        o[nc] = __builtin_amdgcn_mfma_f32_16x16x32_bf16(alo[kc].v, wB[kc][nc].v, o[nc], 0, 0, 0);
      }
#pragma unroll
    for (int nc = 0; nc < 4; ++nc)
#pragma unroll
      for (int r = 0; r < 4; ++r) o[nc][r] = silu_f(o[nc][r]);
    if (COORD) {
#pragma unroll
      for (int r = 0; r < 4; ++r) {
        float v = o[0][r] * cwr[0] + o[1][r] * cwr[1] + o[2][r] * cwr[2] + o[3][r] * cwr[3];
        v += __shfl_xor(v, 1, 64);
        v += __shfl_xor(v, 2, 64);
        v += __shfl_xor(v, 4, 64);
        v += __shfl_xor(v, 8, 64);
        if (m == 0) s_red[w][q * 4 + r] = v;
      }
    }
#pragma unroll
    for (int nc = 0; nc < 4; ++nc)
#pragma unroll
      for (int r = 0; r < 4; ++r)
        s_hs[w][(q * 4 + r) * 76 + nc * 16 + m] = o[nc][r];
    for (int e = 0; e < 16; ++e) {
      const int dv = __shfl(dm, e, 64);
      const float v = s_hs[w][e * 76 + lane];
      if (dv == cur_dst) {
        accum += v;
      } else {
        if (cur_dst >= 0) atomicAdd(&e_agg[(size_t)cur_dst * 64 + lane], accum);
        cur_dst = dv;
        accum = v;
      }
    }
    if (COORD) {
      if (lane < 48) {
        const float s = silu_f(s_red[w][pe] + cb);
        atomicAdd(&cu[(size_t)__shfl(dm, pe, 64) * 3 + pc], s_diff[w][buf][lane] * s);
      }
    }
  }
  if (cur_dst >= 0) atomicAdd(&e_agg[(size_t)cur_dst * 64 + lane], accum);
}

// ------- K3: node MLP via MFMA (3-term split, near-fp32). One 16-node tile/wave.
// L0: + pos update + e_agg rezero + layer-1 P precompute.
// L1: + fused batch mean-pool partials.
template <bool L0>
__global__ __launch_bounds__(256) void k_node(
    const float* __restrict__ x_in, float* __restrict__ e_agg,
    const float* __restrict__ nw1, const float* __restrict__ nb1,
    const float* __restrict__ nw2, const float* __restrict__ nb2,
    const float* __restrict__ pos_in, const float* __restrict__ cu,
    const int* __restrict__ row_ptr,
    float* __restrict__ x_out, float* __restrict__ pos_out,
    const float* __restrict__ Wn, float* __restrict__ P1,
    unsigned short* __restrict__ P2h,
    const int* __restrict__ batch,
    float* __restrict__ g_sum, float* __restrict__ g_cnt) {
  __shared__ __align__(16) float sbuf[4][16 * 132];   // stride 132: 2-way banks (free)
  const int tid = threadIdx.x, w = tid >> 6, lane = tid & 63;
  const int q = lane >> 4, m = lane & 15;
  const int tile = blockIdx.x * 4 + w;
  if (tile >= NTILES) return;
  const int n0 = tile * 16;
  const int nm = n0 + m;
  const bool vm = nm < NN;
  float* sb = sbuf[w];

  // ---- stage 1: A = [x | e_agg] (K=192), split hi/lo ----
  S8 axh[6], axl[6];
#pragma unroll
  for (int kc = 0; kc < 6; ++kc) {
    float hv[8] = {0.f, 0.f, 0.f, 0.f, 0.f, 0.f, 0.f, 0.f};
    if (vm) {
      const float* src = (kc < 4) ? (x_in + (size_t)nm * HIDC + kc * 32 + q * 8)
                                  : (e_agg + (size_t)nm * 64 + (kc - 4) * 32 + q * 8);
      *(f32x4*)&hv[0] = *(const f32x4*)src;
      *(f32x4*)&hv[4] = *(const f32x4*)(src + 4);
    }
    split8(hv, axh[kc], axl[kc]);
  }
  if (L0 && vm) {   // pre-zero e_agg for layer 1 (each lane zeroes exactly what it read)
    const f32x4 z = {0.f, 0.f, 0.f, 0.f};
    float* ez = e_agg + (size_t)nm * 64 + q * 8;
    *(f32x4*)ez = z; *(f32x4*)(ez + 4) = z;
    *(f32x4*)(ez + 32) = z; *(f32x4*)(ez + 36) = z;
  }
  // ---- h1 = silu(A @ nw1 + nb1), N=64 ----
#pragma unroll
  for (int nc = 0; nc < 4; ++nc) {
    const float b = nb1[nc * 16 + m];
    f32x4 acc = {b, b, b, b};
#pragma unroll
    for (int kc = 0; kc < 6; ++kc) {
      S8 bh, bl;
      loadBsplit(nw1, 64, kc * 32, nc * 16, q, m, bh, bl);
      acc = mfma3(axh[kc], axl[kc], bh, bl, acc);
    }
#pragma unroll
    for (int r = 0; r < 4; ++r)
      sb[(q * 4 + r) * 132 + nc * 16 + m] = silu_f(acc[r]);
  }
  // ---- read h1 as A-fragments (same-wave DS ordering), split ----
  S8 ah[2], al[2];
#pragma unroll
  for (int kc = 0; kc < 2; ++kc) {
    float hv[8];
    const float* hp = &sb[m * 132 + kc * 32 + q * 8];
    *(f32x4*)&hv[0] = *(const f32x4*)hp;
    *(f32x4*)&hv[4] = *(const f32x4*)(hp + 4);
    split8(hv, ah[kc], al[kc]);
  }
  // ---- h2 = h1 @ nw2 + nb2, N=128 ----
  f32x4 hh[8];
#pragma unroll
  for (int nc = 0; nc < 8; ++nc) {
    const float b = nb2[nc * 16 + m];
    f32x4 acc = {b, b, b, b};
#pragma unroll
    for (int kc = 0; kc < 2; ++kc) {
      S8 bh, bl;
      loadBsplit(nw2, 128, kc * 32, nc * 16, q, m, bh, bl);
      acc = mfma3(ah[kc], al[kc], bh, bl, acc);
    }
    hh[nc] = acc;
  }
  if (L0) {
    // store x1 + stage to LDS for the P precompute transpose
#pragma unroll
    for (int nc = 0; nc < 8; ++nc)
#pragma unroll
      for (int r = 0; r < 4; ++r) {
        const int n = n0 + q * 4 + r;
        sb[(q * 4 + r) * 132 + nc * 16 + m] = hh[nc][r];
        if (n < NN) x_out[(size_t)n * HIDC + nc * 16 + m] = hh[nc][r];
      }
    // pos update (16 nodes x 3 comps on lanes 0..47)
    if (lane < 48) {
      const int pe2 = lane / 3, pc2 = lane - pe2 * 3;
      const int n = n0 + pe2;
      if (n < NN) {
        const float dg = fmaxf((float)(row_ptr[n + 1] - row_ptr[n]), 1.f);
        pos_out[n * 3 + pc2] = pos_in[n * 3 + pc2] + cu[n * 3 + pc2] / dg;
      }
    }
    // ---- P = x1 @ Wn (rows 0..127 -> P1 fp32, 128..255 -> P2 bf16) ----
    S8 a1h[4], a1l[4];
#pragma unroll
    for (int kc = 0; kc < 4; ++kc) {
      float hv[8];
      const float* hp = &sb[m * 132 + kc * 32 + q * 8];
      *(f32x4*)&hv[0] = *(const f32x4*)hp;
      *(f32x4*)&hv[4] = *(const f32x4*)(hp + 4);
      split8(hv, a1h[kc], a1l[kc]);
    }
#pragma unroll
    for (int nc = 0; nc < 8; ++nc) {
      const float* Wb = Wn + (size_t)(nc < 4 ? 0 : 128 * 64);
      const int ncc = nc & 3;
      f32x4 acc = {0.f, 0.f, 0.f, 0.f};
#pragma unroll
      for (int kc = 0; kc < 4; ++kc) {
        S8 bh, bl;
        loadBsplit(Wb, 64, kc * 32, ncc * 16, q, m, bh, bl);
        acc = mfma3(a1h[kc], a1l[kc], bh, bl, acc);
      }
#pragma unroll
      for (int r = 0; r < 4; ++r) {
        const int n = n0 + q * 4 + r;
        if (n < NN) {
          if (nc < 4) P1[(size_t)n * 64 + ncc * 16 + m] = acc[r];
          else        P2h[(size_t)n * 64 + ncc * 16 + m] = f2bf_rne(acc[r]);
        }
      }
    }
  } else {
    // ---- fused mean-pool partials (batch sorted; run-compress per lane) ----
    int curb = -1;
    float cnt2 = 0.f;
    float pacc[8];
#pragma unroll
    for (int r = 0; r < 4; ++r) {
      const int n = n0 + q * 4 + r;
      if (n < NN) {
        const int bg = batch[n];
        if (bg != curb) {
          if (curb >= 0) {
#pragma unroll
            for (int nc = 0; nc < 8; ++nc)
              atomicAdd(&g_sum[curb * HIDC + nc * 16 + m], pacc[nc]);
            if (m == 0) atomicAdd(&g_cnt[curb], cnt2);
          }
          curb = bg;
#pragma unroll
          for (int nc = 0; nc < 8; ++nc) pacc[nc] = hh[nc][r];
          cnt2 = 1.f;
        } else {
#pragma unroll
          for (int nc = 0; nc < 8; ++nc) pacc[nc] += hh[nc][r];
          cnt2 += 1.f;
        }
      }
    }
    if (curb >= 0) {
#pragma unroll
      for (int nc = 0; nc < 8; ++nc)
        atomicAdd(&g_sum[curb * HIDC + nc * 16 + m], pacc[nc]);
      if (m == 0) atomicAdd(&g_cnt[curb], cnt2);
    }
  }
}

// ---------------- K5: relu(mean) -> relu(@w1+b1) -> @w2+b2 ----------------
__global__ __launch_bounds__(128) void k_final(
    const float* __restrict__ g_sum, const float* __restrict__ g_cnt,
    const float* __restrict__ w1, const float* __restrict__ b1,
    const float* __restrict__ w2, const float* __restrict__ b2,
    float* __restrict__ out) {
  __shared__ float sg[128];
  __shared__ float sh[128];
  const int g = blockIdx.x, j = threadIdx.x;
  const float c = fmaxf(g_cnt[g], 1.f);
  sg[j] = fmaxf(g_sum[g * HIDC + j] / c, 0.f);
  __syncthreads();
  float a = b1[j];
  for (int k = 0; k < 128; ++k) a += sg[k] * w1[k * 128 + j];
  sh[j] = fmaxf(a, 0.f);
  __syncthreads();
  if (j < OUTC) {
    float o = b2[j];
    for (int k = 0; k < 128; ++k) o += sh[k] * w2[k * OUTC + j];
    out[g * OUTC + j] = o;
  }
}

extern "C" void kernel_launch(void* const* d_in, const int* in_sizes, int n_in,
                              void* d_out, int out_size, void* d_ws, size_t ws_size,
                              hipStream_t stream) {
  const float* x     = (const float*)d_in[0];
  const float* pos   = (const float*)d_in[1];
  const float* eattr = (const float*)d_in[2];
  const int*   ei    = (const int*)d_in[3];
  const int*   batch = (const int*)d_in[4];
  const float* mlp_w[2]   = {(const float*)d_in[5],  (const float*)d_in[14]};
  const float* edge_w[2]  = {(const float*)d_in[6],  (const float*)d_in[15]};
  const float* edge_b[2]  = {(const float*)d_in[7],  (const float*)d_in[16]};
  const float* coord_w[2] = {(const float*)d_in[8],  (const float*)d_in[17]};
  const float* coord_b[2] = {(const float*)d_in[9],  (const float*)d_in[18]};
  const float* nw1[2]     = {(const float*)d_in[10], (const float*)d_in[19]};
  const float* nb1[2]     = {(const float*)d_in[11], (const float*)d_in[20]};
  const float* nw2[2]     = {(const float*)d_in[12], (const float*)d_in[21]};
  const float* nb2[2]     = {(const float*)d_in[13], (const float*)d_in[22]};
  const float* ow1 = (const float*)d_in[23];
  const float* ob1 = (const float*)d_in[24];
  const float* ow2 = (const float*)d_in[25];
  const float* ob2 = (const float*)d_in[26];
  float* out = (float*)d_out;

  char* p = (char*)d_ws;
  auto alloc = [&](size_t bytes) {
    void* r = (void*)p;
    p += (bytes + 255) & ~(size_t)255;
    return r;
  };
  float* P1            = (float*)alloc((size_t)NN * 64 * 4);
  unsigned short* P2h  = (unsigned short*)alloc((size_t)NN * 64 * 2);
  // ---- contiguous zero-region (single memset) ----
  char* zero_base      = p;
  float* e_agg         = (float*)alloc((size_t)NN * 64 * 4);
  float* cu            = (float*)alloc((size_t)NN * 3 * 4);
  float* g_sum         = (float*)alloc((size_t)GG * HIDC * 4);
  float* g_cnt         = (float*)alloc((size_t)GG * 4);
  int* cnt             = (int*)alloc((size_t)NN * 4);
  const size_t zero_sz = (size_t)(p - zero_base);
  // ---- non-zeroed scratch ----
  int* row_ptr         = (int*)alloc((size_t)(NN + 1) * 4);
  int* nxt             = (int*)alloc((size_t)NN * 4);
  int* sdst            = (int*)alloc((size_t)EE * 4);
  int* ssrc            = (int*)alloc((size_t)EE * 4);
  int* seid            = (int*)alloc((size_t)EE * 4);
  unsigned short* seah = (unsigned short*)alloc((size_t)EE * DD * 2);
  float* x1            = (float*)alloc((size_t)NN * HIDC * 4);
  float* pos1          = (float*)alloc((size_t)NN * 3 * 4);

  const int edgeBlocks = 1024;   // 4096 waves x (7|6) groups x 16 = 400000 exact
  const int nodeTileBlk = (NTILES + 3) / 4;  // 391

  (void)hipMemsetAsync(zero_base, 0, zero_sz, stream);

  // ---- sort chain + layer-0 precompute (fused into scatter dispatch) ----
  k_hist<<<SCATBLK, 256, 0, stream>>>(ei, cnt);
  k_scan<<<1, 1024, 0, stream>>>(cnt, row_ptr, nxt);
  k_sp<<<NODEBLK + SCATBLK, 256, 0, stream>>>(ei, nxt, sdst, ssrc, seid,
      x, mlp_w[0], P1, P2h);

  // ---- layer 0 ----
  k_edge<true, true><<<edgeBlocks, 256, 0, stream>>>(P1, P2h, pos, eattr,
      seah, seid, sdst, ssrc, mlp_w[0], edge_w[0], edge_b[0],
      coord_w[0], coord_b[0], e_agg, cu);
  k_node<true><<<nodeTileBlk, 256, 0, stream>>>(x, e_agg, nw1[0], nb1[0],
      nw2[0], nb2[0], pos, cu, row_ptr, x1, pos1, mlp_w[1], P1, P2h,
      batch, g_sum, g_cnt);

  // ---- layer 1 ----
  k_edge<false, false><<<edgeBlocks, 256, 0, stream>>>(P1, P2h, pos1, eattr,
      seah, seid, sdst, ssrc, mlp_w[1], edge_w[1], edge_b[1],
      coord_w[1], coord_b[1], e_agg, cu);
  k_node<false><<<nodeTileBlk, 256, 0, stream>>>(x1, e_agg, nw1[1], nb1[1],
      nw2[1], nb2[1], pos1, cu, row_ptr, x1, pos1, mlp_w[1], P1, P2h,
      batch, g_sum, g_cnt);

  // ---- head ----
  k_final<<<GG, 128, 0, stream>>>(g_sum, g_cnt, ow1, ob1, ow2, ob2, out);
}